// Round 1
// 836.980 us; speedup vs baseline: 1.0275x; 1.0275x over previous
//
#include <hip/hip_runtime.h>
#include <math.h>

#define NPB 131072          // pixels per batch element: 4096*32
#define LRELU_SLOPE 0.2f
#define EPSV 1e-6f

typedef __attribute__((ext_vector_type(8))) short short8;   // 8 bf16 = 4 VGPRs
typedef __attribute__((ext_vector_type(4))) float f32x4;    // MFMA C/D frag

static __device__ __forceinline__ unsigned short f2bf_rne(float f) {
    unsigned int u = __float_as_uint(f);
    u += 0x7fffu + ((u >> 16) & 1u);
    return (unsigned short)(u >> 16);
}

// ---- pre-pass: concat the three 1x1-conv weights, split fp32 -> bf16 hi/lo ----
// Layout: W*[o][c], o in [0,80): 64 trans | 8 gate | 8 attn ; c contiguous.
__global__ __launch_bounds__(256) void wt_kernel(
    const float* __restrict__ w_trans,   // [64,128]
    const float* __restrict__ w_gate1,   // [8,128]
    const float* __restrict__ w_attn1,   // [8,128]
    unsigned short* __restrict__ Whi,    // [80][128] bf16 bits
    unsigned short* __restrict__ Wlo)    // [80][128] bf16 bits
{
    int i = blockIdx.x * 256 + threadIdx.x;
    if (i >= 80 * 128) return;
    int o = i >> 7;
    int c = i & 127;
    float v;
    if (o < 64)      v = w_trans[o * 128 + c];
    else if (o < 72) v = w_gate1[(o - 64) * 128 + c];
    else             v = w_attn1[(o - 72) * 128 + c];
    unsigned int u = __float_as_uint(v);
    Whi[i] = (unsigned short)(u >> 16);                    // truncation: residual caught by lo
    float hif = __uint_as_float(u & 0xffff0000u);
    Wlo[i] = f2bf_rne(v - hif);
}

// ---- main fused kernel: 4 waves/block, 32 pixels (= one softmax group) per wave ----
// GEMM y[80][pix] = W[80][128] * x[128][pix] via mfma_f32_16x16x32_bf16, hi/lo split.
// C frag layout (HW-verified): pixel col = lane&15, o row = (lane>>4)*4 + reg.
__global__ __launch_bounds__(256, 3) void gsl_kernel(
    const float* __restrict__ x,                 // [8,128,4096,32]
    const unsigned short* __restrict__ Whi,      // [80][128]
    const unsigned short* __restrict__ Wlo,      // [80][128]
    const float* __restrict__ g_trans, const float* __restrict__ b_trans,
    const float* __restrict__ g_gate,  const float* __restrict__ b_gate,
    const float* __restrict__ w_gate2, const float* __restrict__ b_gate2,
    const float* __restrict__ g_attn,  const float* __restrict__ b_attn,
    const float* __restrict__ w_attn2, const float* __restrict__ b_attn2,
    const float* __restrict__ agg_alpha,
    float* __restrict__ out0,                    // [8,64,4096]
    float* __restrict__ outg)                    // [8,1,4096,32]
{
    const int tid  = threadIdx.x;
    const int wid  = tid >> 6;
    const int lane = tid & 63;
    const int g    = lane >> 4;         // 0..3: k-slot group / o-row group
    const int col  = lane & 15;         // pixel within 16-fragment

    const size_t p0 = (size_t)blockIdx.x * 128 + (size_t)wid * 32;  // wave's first pixel
    const int b   = (int)(p0 >> 17);                                 // p0 / NPB
    const int pin = (int)(p0 & (NPB - 1));
    const int n   = pin >> 5;

    // per-lane x base: batch + pixel-in-batch + fragment column
    const float* xq = x + (size_t)b * 128 * NPB + pin + col;

    f32x4 acc[5][2];
#pragma unroll
    for (int ot = 0; ot < 5; ++ot) {
        acc[ot][0] = (f32x4){0.f, 0.f, 0.f, 0.f};
        acc[ot][1] = (f32x4){0.f, 0.f, 0.f, 0.f};
    }

    // ---- prime the x pipeline: K-step 0 (channels 8g..8g+7, both pixel halves) ----
    float cur[16];
    {
        const int cb = 8 * g;
#pragma unroll
        for (int j = 0; j < 8; ++j) cur[j]     = xq[(size_t)(cb + j) * NPB];
#pragma unroll
        for (int j = 0; j < 8; ++j) cur[8 + j] = xq[(size_t)(cb + j) * NPB + 16];
    }

#pragma unroll 1
    for (int kk = 0; kk < 4; ++kk) {            // c0 = 32*kk
        const int cbase = kk * 32 + 8 * g;

        // prefetch next K-step's x while this step computes
        float nxt[16];
        if (kk < 3) {
            const int cb2 = cbase + 32;
#pragma unroll
            for (int j = 0; j < 8; ++j) nxt[j]     = xq[(size_t)(cb2 + j) * NPB];
#pragma unroll
            for (int j = 0; j < 8; ++j) nxt[8 + j] = xq[(size_t)(cb2 + j) * NPB + 16];
        }

        // A fragments: lane holds W[ot*16+col][cbase .. cbase+7]  (16B aligned)
        short8 ahi[5], alo5[5];
#pragma unroll
        for (int ot = 0; ot < 5; ++ot) {
            const int wof = (ot * 16 + col) * 128 + cbase;
            ahi[ot]  = *(const short8*)(Whi + wof);
            alo5[ot] = *(const short8*)(Wlo + wof);
        }

        // convert cur -> bf16 hi/lo B fragments (pixel halves 0 and 1)
        union U { unsigned int u[4]; short8 s; };
        U bh0, bl0, bh1, bl1;
#pragma unroll
        for (int jj = 0; jj < 4; ++jj) {
            float a0 = cur[2 * jj], a1 = cur[2 * jj + 1];
            unsigned int ua0 = __float_as_uint(a0), ua1 = __float_as_uint(a1);
            bh0.u[jj] = (ua1 & 0xffff0000u) | (ua0 >> 16);
            float r0 = a0 - __uint_as_float(ua0 & 0xffff0000u);
            float r1 = a1 - __uint_as_float(ua1 & 0xffff0000u);
            bl0.u[jj] = ((unsigned int)f2bf_rne(r1) << 16) | (unsigned int)f2bf_rne(r0);

            float c0v = cur[8 + 2 * jj], c1v = cur[8 + 2 * jj + 1];
            unsigned int uc0 = __float_as_uint(c0v), uc1 = __float_as_uint(c1v);
            bh1.u[jj] = (uc1 & 0xffff0000u) | (uc0 >> 16);
            float s0 = c0v - __uint_as_float(uc0 & 0xffff0000u);
            float s1v = c1v - __uint_as_float(uc1 & 0xffff0000u);
            bl1.u[jj] = ((unsigned int)f2bf_rne(s1v) << 16) | (unsigned int)f2bf_rne(s0);
        }

        // 30 MFMAs: hi*hi + lo*hi + hi*lo for both pixel halves
#pragma unroll
        for (int ot = 0; ot < 5; ++ot) {
            acc[ot][0] = __builtin_amdgcn_mfma_f32_16x16x32_bf16(ahi[ot],  bh0.s, acc[ot][0], 0, 0, 0);
            acc[ot][1] = __builtin_amdgcn_mfma_f32_16x16x32_bf16(ahi[ot],  bh1.s, acc[ot][1], 0, 0, 0);
            acc[ot][0] = __builtin_amdgcn_mfma_f32_16x16x32_bf16(alo5[ot], bh0.s, acc[ot][0], 0, 0, 0);
            acc[ot][1] = __builtin_amdgcn_mfma_f32_16x16x32_bf16(alo5[ot], bh1.s, acc[ot][1], 0, 0, 0);
            acc[ot][0] = __builtin_amdgcn_mfma_f32_16x16x32_bf16(ahi[ot],  bl0.s, acc[ot][0], 0, 0, 0);
            acc[ot][1] = __builtin_amdgcn_mfma_f32_16x16x32_bf16(ahi[ot],  bl1.s, acc[ot][1], 0, 0, 0);
        }

        if (kk < 3) {
#pragma unroll
            for (int j = 0; j < 16; ++j) cur[j] = nxt[j];
        }
    }

    // ---- heads: o-tile 4 holds rows 64..79.  g∈{0,1} -> gate h=4g+r ; g∈{2,3} -> attn h=4(g-2)+r
    const bool isGate = (g < 2);
    const int hbase = (g & 1) * 4;
    float hg[4], hb[4], hw[4];
#pragma unroll
    for (int r = 0; r < 4; ++r) {
        const int h = hbase + r;
        hg[r] = isGate ? g_gate[h]  : g_attn[h];
        hb[r] = isGate ? b_gate[h]  : b_attn[h];
        hw[r] = isGate ? w_gate2[h] : w_attn2[h];
    }
    float part0 = 0.f, part1 = 0.f;
#pragma unroll
    for (int r = 0; r < 4; ++r) {
        float v0 = fmaf(acc[4][0][r], hg[r], hb[r]);
        v0 = (v0 >= 0.f) ? v0 : LRELU_SLOPE * v0;
        part0 = fmaf(hw[r], v0, part0);
        float v1 = fmaf(acc[4][1][r], hg[r], hb[r]);
        v1 = (v1 >= 0.f) ? v1 : LRELU_SLOPE * v1;
        part1 = fmaf(hw[r], v1, part1);
    }
    // combine the two 4-element halves of each head, then swap gate<->attn halves
    float t0 = part0 + __shfl_xor(part0, 16);
    float t1 = part1 + __shfl_xor(part1, 16);
    float q0 = __shfl_xor(t0, 32);
    float q1 = __shfl_xor(t1, 32);
    const float bg2 = b_gate2[0], ba2 = b_attn2[0];
    float gl0 = (isGate ? t0 : q0) + bg2;   // gate logit, pixel col
    float gl1 = (isGate ? t1 : q1) + bg2;   // gate logit, pixel col+16
    float al0 = (isGate ? q0 : t0) + ba2;   // attn logit, pixel col
    float al1 = (isGate ? q1 : t1) + ba2;

    if (lane < 16) {                        // one group writes gate_logits (coalesced 64B x2)
        outg[p0 + col]      = gl0;
        outg[p0 + 16 + col] = gl1;
    }

    // ---- group (32-pixel) softmax + mask + renorm, replicated in every lane ----
    float m = fmaxf(al0, al1);
#pragma unroll
    for (int s = 1; s < 16; s <<= 1) m = fmaxf(m, __shfl_xor(m, s));
    float e0 = expf(al0 - m), e1 = expf(al1 - m);
    float w0m = (gl0 >= 0.f) ? e0 : 0.f;
    float w1m = (gl1 >= 0.f) ? e1 : 0.f;
    float s1 = e0 + e1;
    float sm = w0m + w1m;
#pragma unroll
    for (int s = 1; s < 16; s <<= 1) {
        s1 += __shfl_xor(s1, s);
        sm += __shfl_xor(sm, s);
    }
    // ref: w = (mask*e/S1) / (sum(mask*e)/S1 + EPS)  ==  mask*e / (SM + EPS*S1)
    const float inv = 1.f / (sm + EPSV * s1);
    const float wgt0 = w0m * inv;
    const float wgt1 = w1m * inv;

    const float aa = agg_alpha[0];
    const float alpha = 1.f / (1.f + expf(-aa));
    const float beta  = 1.f - alpha;

    // ---- trans epilogue: affine+lrelu, weighted-sum and max over the 32-pixel group ----
    float* outb = out0 + (size_t)b * 64 * 4096 + n;
#pragma unroll
    for (int ot = 0; ot < 4; ++ot) {
#pragma unroll
        for (int r = 0; r < 4; ++r) {
            const int o = ot * 16 + 4 * g + r;
            const float gt = g_trans[o], bt = b_trans[o];
            float v0 = fmaf(acc[ot][0][r], gt, bt);
            v0 = (v0 >= 0.f) ? v0 : LRELU_SLOPE * v0;
            float v1 = fmaf(acc[ot][1][r], gt, bt);
            v1 = (v1 >= 0.f) ? v1 : LRELU_SLOPE * v1;
            float sv = fmaf(v0, wgt0, v1 * wgt1);
            float mv = fmaxf(v0, v1);
#pragma unroll
            for (int s = 1; s < 16; s <<= 1) {
                sv += __shfl_xor(sv, s);
                mv = fmaxf(mv, __shfl_xor(mv, s));
            }
            if (col == 0)
                outb[(size_t)o * 4096] = fmaf(alpha, sv, beta * mv);
        }
    }
}

extern "C" void kernel_launch(void* const* d_in, const int* in_sizes, int n_in,
                              void* d_out, int out_size, void* d_ws, size_t ws_size,
                              hipStream_t stream) {
    const float* x        = (const float*)d_in[0];
    const float* w_trans  = (const float*)d_in[1];
    const float* g_trans  = (const float*)d_in[2];
    const float* b_trans  = (const float*)d_in[3];
    const float* w_gate1  = (const float*)d_in[4];
    const float* g_gate   = (const float*)d_in[5];
    const float* b_gate   = (const float*)d_in[6];
    const float* w_gate2  = (const float*)d_in[7];
    const float* b_gate2  = (const float*)d_in[8];
    const float* w_attn1  = (const float*)d_in[9];
    const float* g_attn   = (const float*)d_in[10];
    const float* b_attn   = (const float*)d_in[11];
    const float* w_attn2  = (const float*)d_in[12];
    const float* b_attn2  = (const float*)d_in[13];
    const float* agg_alpha= (const float*)d_in[14];

    float* out0 = (float*)d_out;                       // [8,64,4096]
    float* outg = (float*)d_out + (size_t)8*64*4096;   // [8,1,4096,32]
    unsigned short* Whi = (unsigned short*)d_ws;       // [80][128]
    unsigned short* Wlo = Whi + 80 * 128;              // [80][128]

    wt_kernel<<<(80*128 + 255)/256, 256, 0, stream>>>(w_trans, w_gate1, w_attn1, Whi, Wlo);

    const int npix = 8 * NPB;                          // 1,048,576 pixels
    gsl_kernel<<<npix / 128, 256, 0, stream>>>(        // 8192 blocks, 4 waves each
        x, Whi, Wlo, g_trans, b_trans, g_gate, b_gate, w_gate2, b_gate2,
        g_attn, b_attn, w_attn2, b_attn2, agg_alpha, out0, outg);
}

// Round 2
// 821.123 us; speedup vs baseline: 1.0473x; 1.0193x over previous
//
#include <hip/hip_runtime.h>
#include <hip/hip_bf16.h>
#include <math.h>

#define NPB 131072          // pixels per batch element: 4096*32
#define LRELU_SLOPE 0.2f
#define EPSV 1e-6f

typedef __attribute__((ext_vector_type(8))) short short8;   // 8 bf16 = 4 VGPRs
typedef __attribute__((ext_vector_type(4))) float f32x4;    // MFMA C/D frag

static __device__ __forceinline__ unsigned short f2bf_rne(float f) {
    unsigned int u = __float_as_uint(f);
    u += 0x7fffu + ((u >> 16) & 1u);
    return (unsigned short)(u >> 16);
}

// pack two fp32 residuals -> packed bf16x2 (RNE); compiler emits v_cvt_pk_bf16_f32
static __device__ __forceinline__ unsigned int cvt_pk_bf16(float f0, float f1) {
    __hip_bfloat162 h = __float22bfloat162_rn(make_float2(f0, f1));
    unsigned int r;
    __builtin_memcpy(&r, &h, 4);
    return r;
}

// ---- pre-pass: concat the three 1x1-conv weights, split fp32 -> bf16 hi/lo ----
// Layout: W*[o][c], o in [0,80): 64 trans | 8 gate | 8 attn ; c contiguous.
__global__ __launch_bounds__(256) void wt_kernel(
    const float* __restrict__ w_trans,   // [64,128]
    const float* __restrict__ w_gate1,   // [8,128]
    const float* __restrict__ w_attn1,   // [8,128]
    unsigned short* __restrict__ Whi,    // [80][128] bf16 bits
    unsigned short* __restrict__ Wlo)    // [80][128] bf16 bits
{
    int i = blockIdx.x * 256 + threadIdx.x;
    if (i >= 80 * 128) return;
    int o = i >> 7;
    int c = i & 127;
    float v;
    if (o < 64)      v = w_trans[o * 128 + c];
    else if (o < 72) v = w_gate1[(o - 64) * 128 + c];
    else             v = w_attn1[(o - 72) * 128 + c];
    unsigned int u = __float_as_uint(v);
    Whi[i] = (unsigned short)(u >> 16);                    // truncation: residual caught by lo
    float hif = __uint_as_float(u & 0xffff0000u);
    Wlo[i] = f2bf_rne(v - hif);
}

// ---- main fused kernel: 4 waves/block, 32 pixels (= one softmax group) per wave ----
// GEMM y[80][pix] = W[80][128] * x[128][pix] via mfma_f32_16x16x32_bf16, hi/lo split.
// C frag layout (HW-verified): pixel col = lane&15, o row = (lane>>4)*4 + reg.
__global__ __launch_bounds__(256, 4) void gsl_kernel(
    const float* __restrict__ x,                 // [8,128,4096,32]
    const unsigned short* __restrict__ Whi,      // [80][128]
    const unsigned short* __restrict__ Wlo,      // [80][128]
    const float* __restrict__ g_trans, const float* __restrict__ b_trans,
    const float* __restrict__ g_gate,  const float* __restrict__ b_gate,
    const float* __restrict__ w_gate2, const float* __restrict__ b_gate2,
    const float* __restrict__ g_attn,  const float* __restrict__ b_attn,
    const float* __restrict__ w_attn2, const float* __restrict__ b_attn2,
    const float* __restrict__ agg_alpha,
    float* __restrict__ out0,                    // [8,64,4096]
    float* __restrict__ outg)                    // [8,1,4096,32]
{
    const int tid  = threadIdx.x;
    const int wid  = tid >> 6;
    const int lane = tid & 63;
    const int g    = lane >> 4;         // 0..3: k-slot group / o-row group
    const int col  = lane & 15;         // pixel within 16-fragment

    const size_t p0 = (size_t)blockIdx.x * 128 + (size_t)wid * 32;  // wave's first pixel
    const int b   = (int)(p0 >> 17);                                 // p0 / NPB
    const int pin = (int)(p0 & (NPB - 1));
    const int n   = pin >> 5;

    // per-lane x base: batch + pixel-in-batch + fragment column
    const float* xq = x + (size_t)b * 128 * NPB + pin + col;

    f32x4 acc[5][2];
#pragma unroll
    for (int ot = 0; ot < 5; ++ot) {
        acc[ot][0] = (f32x4){0.f, 0.f, 0.f, 0.f};
        acc[ot][1] = (f32x4){0.f, 0.f, 0.f, 0.f};
    }

    // ---- K loop: fully unrolled; scheduler hoists loads, TLP (4 waves/SIMD) hides HBM ----
#pragma unroll
    for (int kk = 0; kk < 4; ++kk) {
        const int cbase = kk * 32 + 8 * g;   // this lane-group's 8-channel K-chunk

        float xv[16];
#pragma unroll
        for (int j = 0; j < 8; ++j) xv[j]     = xq[(size_t)(cbase + j) * NPB];
#pragma unroll
        for (int j = 0; j < 8; ++j) xv[8 + j] = xq[(size_t)(cbase + j) * NPB + 16];

        // convert -> bf16 hi/lo B fragments: 1 v_perm (hi pack) + 2 sub + 1 cvt_pk (lo) per pair
        union U { unsigned int u[4]; short8 s; };
        U bh0, bl0, bh1, bl1;
#pragma unroll
        for (int jj = 0; jj < 4; ++jj) {
            float a0 = xv[2 * jj], a1 = xv[2 * jj + 1];
            unsigned int ua0 = __float_as_uint(a0), ua1 = __float_as_uint(a1);
            bh0.u[jj] = __builtin_amdgcn_perm(ua1, ua0, 0x07060302u);   // (ua1&hi)|(ua0>>16)
            bl0.u[jj] = cvt_pk_bf16(a0 - __uint_as_float(ua0 & 0xffff0000u),
                                    a1 - __uint_as_float(ua1 & 0xffff0000u));

            float c0v = xv[8 + 2 * jj], c1v = xv[8 + 2 * jj + 1];
            unsigned int uc0 = __float_as_uint(c0v), uc1 = __float_as_uint(c1v);
            bh1.u[jj] = __builtin_amdgcn_perm(uc1, uc0, 0x07060302u);
            bl1.u[jj] = cvt_pk_bf16(c0v - __uint_as_float(uc0 & 0xffff0000u),
                                    c1v - __uint_as_float(uc1 & 0xffff0000u));
        }

        // per-ot: load A frags just-in-time (short liveness), 6 MFMAs each
#pragma unroll
        for (int ot = 0; ot < 5; ++ot) {
            const int wof = (ot * 16 + col) * 128 + cbase;
            short8 ahi = *(const short8*)(Whi + wof);
            short8 alo = *(const short8*)(Wlo + wof);
            acc[ot][0] = __builtin_amdgcn_mfma_f32_16x16x32_bf16(ahi, bh0.s, acc[ot][0], 0, 0, 0);
            acc[ot][1] = __builtin_amdgcn_mfma_f32_16x16x32_bf16(ahi, bh1.s, acc[ot][1], 0, 0, 0);
            acc[ot][0] = __builtin_amdgcn_mfma_f32_16x16x32_bf16(alo, bh0.s, acc[ot][0], 0, 0, 0);
            acc[ot][1] = __builtin_amdgcn_mfma_f32_16x16x32_bf16(alo, bh1.s, acc[ot][1], 0, 0, 0);
            acc[ot][0] = __builtin_amdgcn_mfma_f32_16x16x32_bf16(ahi, bl0.s, acc[ot][0], 0, 0, 0);
            acc[ot][1] = __builtin_amdgcn_mfma_f32_16x16x32_bf16(ahi, bl1.s, acc[ot][1], 0, 0, 0);
        }
    }

    // ---- heads: o-tile 4 holds rows 64..79.  g∈{0,1} -> gate h=4g+r ; g∈{2,3} -> attn h=4(g-2)+r
    const bool isGate = (g < 2);
    const int hbase = (g & 1) * 4;
    float hg[4], hb[4], hw[4];
#pragma unroll
    for (int r = 0; r < 4; ++r) {
        const int h = hbase + r;
        hg[r] = isGate ? g_gate[h]  : g_attn[h];
        hb[r] = isGate ? b_gate[h]  : b_attn[h];
        hw[r] = isGate ? w_gate2[h] : w_attn2[h];
    }
    float part0 = 0.f, part1 = 0.f;
#pragma unroll
    for (int r = 0; r < 4; ++r) {
        float v0 = fmaf(acc[4][0][r], hg[r], hb[r]);
        v0 = (v0 >= 0.f) ? v0 : LRELU_SLOPE * v0;
        part0 = fmaf(hw[r], v0, part0);
        float v1 = fmaf(acc[4][1][r], hg[r], hb[r]);
        v1 = (v1 >= 0.f) ? v1 : LRELU_SLOPE * v1;
        part1 = fmaf(hw[r], v1, part1);
    }
    // combine the two 4-element halves of each head, then swap gate<->attn halves
    float t0 = part0 + __shfl_xor(part0, 16);
    float t1 = part1 + __shfl_xor(part1, 16);
    float q0 = __shfl_xor(t0, 32);
    float q1 = __shfl_xor(t1, 32);
    const float bg2 = b_gate2[0], ba2 = b_attn2[0];
    float gl0 = (isGate ? t0 : q0) + bg2;   // gate logit, pixel col
    float gl1 = (isGate ? t1 : q1) + bg2;   // gate logit, pixel col+16
    float al0 = (isGate ? q0 : t0) + ba2;   // attn logit, pixel col
    float al1 = (isGate ? q1 : t1) + ba2;

    if (lane < 16) {                        // one group writes gate_logits (coalesced 64B x2)
        outg[p0 + col]      = gl0;
        outg[p0 + 16 + col] = gl1;
    }

    // ---- group (32-pixel) softmax + mask + renorm, replicated in every lane ----
    float m = fmaxf(al0, al1);
#pragma unroll
    for (int s = 1; s < 16; s <<= 1) m = fmaxf(m, __shfl_xor(m, s));
    float e0 = expf(al0 - m), e1 = expf(al1 - m);
    float w0m = (gl0 >= 0.f) ? e0 : 0.f;
    float w1m = (gl1 >= 0.f) ? e1 : 0.f;
    float s1 = e0 + e1;
    float sm = w0m + w1m;
#pragma unroll
    for (int s = 1; s < 16; s <<= 1) {
        s1 += __shfl_xor(s1, s);
        sm += __shfl_xor(sm, s);
    }
    // ref: w = (mask*e/S1) / (sum(mask*e)/S1 + EPS)  ==  mask*e / (SM + EPS*S1)
    const float inv = 1.f / (sm + EPSV * s1);
    const float wgt0 = w0m * inv;
    const float wgt1 = w1m * inv;

    const float aa = agg_alpha[0];
    const float alpha = 1.f / (1.f + expf(-aa));
    const float beta  = 1.f - alpha;

    // ---- trans epilogue: affine+lrelu, weighted-sum and max over the 32-pixel group ----
    float* outb = out0 + (size_t)b * 64 * 4096 + n;
#pragma unroll
    for (int ot = 0; ot < 4; ++ot) {
#pragma unroll
        for (int r = 0; r < 4; ++r) {
            const int o = ot * 16 + 4 * g + r;
            const float gt = g_trans[o], bt = b_trans[o];
            float v0 = fmaf(acc[ot][0][r], gt, bt);
            v0 = (v0 >= 0.f) ? v0 : LRELU_SLOPE * v0;
            float v1 = fmaf(acc[ot][1][r], gt, bt);
            v1 = (v1 >= 0.f) ? v1 : LRELU_SLOPE * v1;
            float sv = fmaf(v0, wgt0, v1 * wgt1);
            float mv = fmaxf(v0, v1);
#pragma unroll
            for (int s = 1; s < 16; s <<= 1) {
                sv += __shfl_xor(sv, s);
                mv = fmaxf(mv, __shfl_xor(mv, s));
            }
            if (col == 0)
                outb[(size_t)o * 4096] = fmaf(alpha, sv, beta * mv);
        }
    }
}

extern "C" void kernel_launch(void* const* d_in, const int* in_sizes, int n_in,
                              void* d_out, int out_size, void* d_ws, size_t ws_size,
                              hipStream_t stream) {
    const float* x        = (const float*)d_in[0];
    const float* w_trans  = (const float*)d_in[1];
    const float* g_trans  = (const float*)d_in[2];
    const float* b_trans  = (const float*)d_in[3];
    const float* w_gate1  = (const float*)d_in[4];
    const float* g_gate   = (const float*)d_in[5];
    const float* b_gate   = (const float*)d_in[6];
    const float* w_gate2  = (const float*)d_in[7];
    const float* b_gate2  = (const float*)d_in[8];
    const float* w_attn1  = (const float*)d_in[9];
    const float* g_attn   = (const float*)d_in[10];
    const float* b_attn   = (const float*)d_in[11];
    const float* w_attn2  = (const float*)d_in[12];
    const float* b_attn2  = (const float*)d_in[13];
    const float* agg_alpha= (const float*)d_in[14];

    float* out0 = (float*)d_out;                       // [8,64,4096]
    float* outg = (float*)d_out + (size_t)8*64*4096;   // [8,1,4096,32]
    unsigned short* Whi = (unsigned short*)d_ws;       // [80][128]
    unsigned short* Wlo = Whi + 80 * 128;              // [80][128]

    wt_kernel<<<(80*128 + 255)/256, 256, 0, stream>>>(w_trans, w_gate1, w_attn1, Whi, Wlo);

    const int npix = 8 * NPB;                          // 1,048,576 pixels
    gsl_kernel<<<npix / 128, 256, 0, stream>>>(        // 8192 blocks, 4 waves each
        x, Whi, Wlo, g_trans, b_trans, g_gate, b_gate, w_gate2, b_gate2,
        g_attn, b_attn, w_attn2, b_attn2, agg_alpha, out0, outg);
}